// Round 5
// baseline (431.628 us; speedup 1.0000x reference)
//
#include <hip/hip_runtime.h>

// GraphConvolution: out = segment_sum_dst( w_e * (x @ W)[src_e] )
// N=100000 nodes, E=3200000 edges, D_IN=256, D_OUT=128, fp32 in/out.
// support stored bf16 row-major [N][128].
// GEMM (v4): bf16 MFMA 16x16x32, LDS-free, 16 rows/wave (was 32).
//   Round-4 counters: 66us, MfmaUtil 3.6%, VALUBusy 9%, Occ 14.9%, 1.2TB/s
//   -> latency-bound at 3 waves/SIMD (782 blocks). Halving rows/wave
//   doubles grid to 1563 blocks (~24 waves/CU); x still read exactly once;
//   B traffic doubles but Wt (64KB) is L2-resident.
// SpMM: TWO sequential column-half passes (12.8MB gather footprint each ->
//       higher per-XCD L2 hit rate); CSR recs 4B (src17|w15 fixed-point).
// CSR build (v3): chunked two-phase per-SB sort, LDS atomics ONLY.
//   LESSON (round 1): O(E) global atomics = device-scope RMW at the
//   coherence point (~64B HBM-side op each) -> 195MB traffic, 178us. Never.

#define DIN 256
#define DOUT 128
#define SB_SHIFT 10
#define SB_NODES 1024
#define MAX_NSB 128
#define TILE 4096
#define CH 8

__device__ __forceinline__ unsigned pack_bf16x2(float a, float b) {
  unsigned ua = __float_as_uint(a);
  unsigned ub = __float_as_uint(b);
  ua += 0x7fffu + ((ua >> 16) & 1u);   // round-to-nearest-even
  ub += 0x7fffu + ((ub >> 16) & 1u);
  return (ua >> 16) | (ub & 0xffff0000u);
}
__device__ __forceinline__ unsigned short bf16_rne(float a) {
  unsigned ua = __float_as_uint(a);
  ua += 0x7fffu + ((ua >> 16) & 1u);
  return (unsigned short)(ua >> 16);
}
__device__ __forceinline__ float bf_lo(unsigned p) { return __uint_as_float(p << 16); }
__device__ __forceinline__ float bf_hi(unsigned p) { return __uint_as_float(p & 0xffff0000u); }

typedef __attribute__((ext_vector_type(8))) short bf16x8;
typedef __attribute__((ext_vector_type(4))) float f32x4;

// ---------------- W transpose: W[256][128] fp32 -> Wt[128][256] bf16 -------
__global__ __launch_bounds__(256) void wtrans_kernel(const float* __restrict__ W,
                                                     unsigned short* __restrict__ Wt) {
  __shared__ float s[64][65];
  int t = threadIdx.x;
  int kt = blockIdx.x >> 1;
  int nt = blockIdx.x & 1;
#pragma unroll
  for (int i = 0; i < 16; i++) {
    int idx = i * 256 + t;
    int kk = idx >> 6, nn = idx & 63;
    s[kk][nn] = W[(size_t)(kt * 64 + kk) * DOUT + nt * 64 + nn];
  }
  __syncthreads();
#pragma unroll
  for (int i = 0; i < 16; i++) {
    int idx = i * 256 + t;
    int nn = idx >> 6, kk = idx & 63;
    Wt[(size_t)(nt * 64 + nn) * DIN + kt * 64 + kk] = bf16_rne(s[kk][nn]);
  }
}

// ---------------- GEMM: support = x @ W via bf16 MFMA, no LDS --------------
// v4: 16 rows per wave, 64 rows per block -> 1563 blocks for latency hiding.
__global__ __launch_bounds__(256) void gemm_mfma_kernel(const float* __restrict__ x,
                                                        const unsigned short* __restrict__ Wt,
                                                        unsigned short* __restrict__ support,
                                                        int M) {
  const int lane = threadIdx.x & 63;
  const int wave = threadIdx.x >> 6;
  const int m = lane & 15, kg = lane >> 4;
  const int rowBase = blockIdx.x * 64 + wave * 16;

  f32x4 acc[8];
#pragma unroll
  for (int ct = 0; ct < 8; ct++) acc[ct] = (f32x4)(0.f);

  int r = rowBase + m;
  if (r > M - 1) r = M - 1;
  const float* arow = x + (size_t)r * DIN + kg * 8;
  const unsigned short* brow[8];
#pragma unroll
  for (int ct = 0; ct < 8; ct++)
    brow[ct] = Wt + (size_t)(ct * 16 + m) * DIN + kg * 8;

#pragma unroll 2
  for (int k0 = 0; k0 < DIN; k0 += 32) {
    float4 a0 = *(const float4*)(arow + k0);
    float4 a1 = *(const float4*)(arow + k0 + 4);
    union { bf16x8 f; unsigned u[4]; } ua;
    ua.u[0] = pack_bf16x2(a0.x, a0.y);
    ua.u[1] = pack_bf16x2(a0.z, a0.w);
    ua.u[2] = pack_bf16x2(a1.x, a1.y);
    ua.u[3] = pack_bf16x2(a1.z, a1.w);
    bf16x8 af = ua.f;
    bf16x8 bfr[8];
#pragma unroll
    for (int ct = 0; ct < 8; ct++) {
      union { bf16x8 f; uint4 u; } ub;
      ub.u = *(const uint4*)(brow[ct] + k0);
      bfr[ct] = ub.f;
    }
#pragma unroll
    for (int ct = 0; ct < 8; ct++)
      acc[ct] = __builtin_amdgcn_mfma_f32_16x16x32_bf16(af, bfr[ct], acc[ct], 0, 0, 0);
  }

#pragma unroll
  for (int r4 = 0; r4 < 4; r4++) {
    int row = rowBase + kg * 4 + r4;
    if (row < M) {
#pragma unroll
      for (int ct = 0; ct < 8; ct++) {
        int col = ct * 16 + m;
        support[(size_t)row * DOUT + col] = bf16_rne(acc[ct][r4]);
      }
    }
  }
}

// ---------------- super-bucket totals (LDS histogram, 98 counters) ---------
__global__ __launch_bounds__(256) void sbhist_kernel(const int* __restrict__ dst, int E,
                                                     int nsb, int* __restrict__ sb_tot) {
  __shared__ int h[MAX_NSB];
  int t = threadIdx.x;
  for (int i = t; i < nsb; i += 256) h[i] = 0;
  __syncthreads();
  int e4 = E >> 2;
  for (int i = blockIdx.x * 256 + t; i < e4; i += gridDim.x * 256) {
    int4 d = *(const int4*)&dst[i * 4];
    atomicAdd(&h[d.x >> SB_SHIFT], 1);
    atomicAdd(&h[d.y >> SB_SHIFT], 1);
    atomicAdd(&h[d.z >> SB_SHIFT], 1);
    atomicAdd(&h[d.w >> SB_SHIFT], 1);
  }
  if (blockIdx.x == 0 && t < (E & 3)) atomicAdd(&h[dst[e4 * 4 + t] >> SB_SHIFT], 1);
  __syncthreads();
  for (int i = t; i < nsb; i += 256)
    if (h[i]) atomicAdd(&sb_tot[i], h[i]);
}

// ---------------- exclusive scan of <=128 SB totals ------------------------
__global__ __launch_bounds__(128) void sbscan_kernel(const int* __restrict__ sb_tot, int nsb,
                                                     int* __restrict__ sb_base,
                                                     int* __restrict__ sb_cur) {
  __shared__ int s[128];
  int t = threadIdx.x;
  int v = (t < nsb) ? sb_tot[t] : 0;
  s[t] = v;
  __syncthreads();
  for (int off = 1; off < 128; off <<= 1) {
    int u = (t >= off) ? s[t - off] : 0;
    __syncthreads();
    s[t] += u;
    __syncthreads();
  }
  if (t < nsb) {
    int excl = s[t] - v;
    sb_base[t] = excl;
    sb_cur[t] = excl;
  }
}

// ---------------- bin1: LDS counting-sort by SB, coalesced chunk flush -----
// Emits split arrays: binq (final csr word src17|wq15) + binl (u16 local id).
__global__ __launch_bounds__(256) void bin1_kernel(const int* __restrict__ src,
                                                   const int* __restrict__ dst,
                                                   const float* __restrict__ w,
                                                   int E, int nsb,
                                                   int* __restrict__ sb_cur,
                                                   unsigned* __restrict__ binq,
                                                   unsigned short* __restrict__ binl) {
  __shared__ unsigned lq[TILE];
  __shared__ unsigned short ll[TILE];
  __shared__ unsigned short sbid[TILE];
  __shared__ int hist[MAX_NSB], segstart[MAX_NSB], cursor[MAX_NSB], sbbase[MAX_NSB];
  __shared__ int sc[128];
  int t = threadIdx.x;
  int e0 = blockIdx.x * TILE;
  int cnt = min(TILE, E - e0);

  for (int i = t; i < nsb; i += 256) hist[i] = 0;
  __syncthreads();
  for (int k = 0; k < TILE / 256; k++) {
    int e = e0 + k * 256 + t;
    if (e < E) atomicAdd(&hist[dst[e] >> SB_SHIFT], 1);
  }
  __syncthreads();
  if (t < 128) sc[t] = (t < nsb) ? hist[t] : 0;
  __syncthreads();
  for (int off = 1; off < 128; off <<= 1) {
    int v = 0;
    if (t < 128 && t >= off) v = sc[t - off];
    __syncthreads();
    if (t < 128) sc[t] += v;
    __syncthreads();
  }
  if (t < nsb) {
    int c = hist[t];
    int excl = sc[t] - c;
    segstart[t] = excl;
    cursor[t] = excl;
    if (c > 0) sbbase[t] = atomicAdd(&sb_cur[t], c);
  }
  __syncthreads();
  for (int k = 0; k < TILE / 256; k++) {
    int e = e0 + k * 256 + t;
    if (e < E) {
      int d = dst[e];
      int sb = d >> SB_SHIFT;
      int slot = atomicAdd(&cursor[sb], 1);
      float wf = w[e];
      unsigned wq = (unsigned)(wf * 32767.f + 0.5f);
      if (wq > 32767u) wq = 32767u;
      lq[slot] = (unsigned)src[e] | (wq << 17);
      ll[slot] = (unsigned short)(d & (SB_NODES - 1));
      sbid[slot] = (unsigned short)sb;
    }
  }
  __syncthreads();
  for (int k = 0; k < TILE / 256; k++) {
    int slot = k * 256 + t;
    if (slot < cnt) {
      int sb = sbid[slot];
      int p = sbbase[sb] + (slot - segstart[sb]);
      binq[p] = lq[slot];
      binl[p] = ll[slot];
    }
  }
}

// ---- XCD-grouped (sb,chunk) mapping: blockIdx ≡ sb (mod 8) so all 8 ------
// chunks of one SB land on the same XCD (csr window stays in one L2).
__device__ __forceinline__ bool sb_chunk(int g, int nsb, int nsb8, int& sb, int& c) {
  int xcd = g & 7;
  int i = g >> 3;
  sb = xcd + 8 * (i % nsb8);
  c = i / nsb8;
  return sb < nsb;
}

// ---------------- histC: per-(SB,chunk) node histogram (LDS) ---------------
__global__ __launch_bounds__(256) void histC_kernel(const unsigned short* __restrict__ binl,
                                                    const int* __restrict__ sb_base,
                                                    const int* __restrict__ sb_tot,
                                                    int nsb, int nsb8,
                                                    int* __restrict__ chist) {
  __shared__ int h[SB_NODES];
  int sb, c;
  if (!sb_chunk(blockIdx.x, nsb, nsb8, sb, c)) return;
  int t = threadIdx.x;
  for (int l = t; l < SB_NODES; l += 256) h[l] = 0;
  __syncthreads();
  int beg = sb_base[sb], len = sb_tot[sb];
  int per = (len + CH - 1) / CH;
  int lo = beg + min(len, c * per);
  int hi = beg + min(len, (c + 1) * per);
  for (int e = lo + t; e < hi; e += 256)
    atomicAdd(&h[binl[e]], 1);
  __syncthreads();
  int* dstp = chist + ((size_t)sb * CH + c) * SB_NODES;
  for (int l = t; l < SB_NODES; l += 256) dstp[l] = h[l];
}

// ---------------- rowscanC: per-SB scan -> row_ptr + absolute cursors ------
__global__ __launch_bounds__(256) void rowscanC_kernel(int* __restrict__ chist,
                                                       const int* __restrict__ sb_base,
                                                       int N, int E, int nsb,
                                                       int* __restrict__ row_ptr) {
  __shared__ int part[256];
  int sb = blockIdx.x;
  int t = threadIdx.x;
  int* base = chist + (size_t)sb * CH * SB_NODES;
  int cnt[4][CH];
  int tsum = 0;
#pragma unroll
  for (int u = 0; u < 4; u++) {
    int l = 4 * t + u;
#pragma unroll
    for (int c = 0; c < CH; c++) {
      int v = base[c * SB_NODES + l];
      cnt[u][c] = v;
      tsum += v;
    }
  }
  part[t] = tsum;
  __syncthreads();
  for (int off = 1; off < 256; off <<= 1) {
    int v = (t >= off) ? part[t - off] : 0;
    __syncthreads();
    part[t] += v;
    __syncthreads();
  }
  int run = sb_base[sb] + part[t] - tsum;
  int nodeBase = sb << SB_SHIFT;
#pragma unroll
  for (int u = 0; u < 4; u++) {
    int l = 4 * t + u;
    int node = nodeBase + l;
    if (node < N) row_ptr[node] = run;
#pragma unroll
    for (int c = 0; c < CH; c++) {
      base[c * SB_NODES + l] = run;
      run += cnt[u][c];
    }
  }
  if (sb == nsb - 1 && t == 0) row_ptr[N] = E;
}

// ---------------- scatterC: single read, LDS cursors, direct csr copy ------
__global__ __launch_bounds__(256) void scatterC_kernel(const unsigned* __restrict__ binq,
                                                       const unsigned short* __restrict__ binl,
                                                       const int* __restrict__ sb_base,
                                                       const int* __restrict__ sb_tot,
                                                       const int* __restrict__ chist,
                                                       int nsb, int nsb8,
                                                       unsigned* __restrict__ csr) {
  __shared__ int cur[SB_NODES];
  int sb, c;
  if (!sb_chunk(blockIdx.x, nsb, nsb8, sb, c)) return;
  int t = threadIdx.x;
  const int* cb = chist + ((size_t)sb * CH + c) * SB_NODES;
  for (int l = t; l < SB_NODES; l += 256) cur[l] = cb[l];
  __syncthreads();
  int beg = sb_base[sb], len = sb_tot[sb];
  int per = (len + CH - 1) / CH;
  int lo = beg + min(len, c * per);
  int hi = beg + min(len, (c + 1) * per);
  for (int e = lo + t; e < hi; e += 256) {
    int l = binl[e];
    int pos = atomicAdd(&cur[l], 1);
    csr[pos] = binq[e];
  }
}

// ---------------- gather SpMM v3: column-half pass, wave per node ----------
// pass p gathers only 128B (cols p*64..p*64+63) per edge -> 12.8MB footprint.
// wave = 4 edge-groups x 16 col-lanes; lane loads uint2 (4 cols).
__global__ __launch_bounds__(256) void spmm_kernel(const unsigned* __restrict__ sup,
                                                   const int* __restrict__ row_ptr,
                                                   const unsigned* __restrict__ csr,
                                                   float* __restrict__ out, int N,
                                                   int pass) {
  int wave = threadIdx.x >> 6;
  int lane = threadIdx.x & 63;
  int g = lane >> 4;        // edge subgroup 0..3
  int c = lane & 15;        // col chunk: uint2 -> cols pass*64 + c*4 ..+3
  int node = blockIdx.x * 4 + wave;
  if (node >= N) return;
  int j0 = row_ptr[node];
  int j1 = row_ptr[node + 1];
  const unsigned* supb = sup + pass * 32 + c * 2;
  float acc[4] = {0.f, 0.f, 0.f, 0.f};
  const float wscale = 1.f / 32767.f;

  for (int base = j0; base < j1; base += 64) {
    int cnt = min(64, j1 - base);
    unsigned myrec = 0;
    if (lane < cnt) myrec = csr[base + lane];
    for (int j = 0; j < cnt; j += 16) {
      uint2 p[4];
      float wv[4];
#pragma unroll
      for (int u = 0; u < 4; u++) {
        int e = j + 4 * u + g;
        int jj = min(e, cnt - 1);
        unsigned r = (unsigned)__shfl((int)myrec, jj, 64);
        int s = (int)(r & 0x1FFFFu);
        float ww = (float)(r >> 17) * wscale;
        wv[u] = (e < cnt) ? ww : 0.f;
        p[u] = *(const uint2*)(supb + (size_t)s * 64);
      }
#pragma unroll
      for (int u = 0; u < 4; u++) {
        acc[0] += wv[u] * bf_lo(p[u].x);
        acc[1] += wv[u] * bf_hi(p[u].x);
        acc[2] += wv[u] * bf_lo(p[u].y);
        acc[3] += wv[u] * bf_hi(p[u].y);
      }
    }
  }
#pragma unroll
  for (int i = 0; i < 4; i++) {
    acc[i] += __shfl_xor(acc[i], 16, 64);
    acc[i] += __shfl_xor(acc[i], 32, 64);
  }
  if (g == 0) {
    float* orow = out + (size_t)node * DOUT + pass * 64 + c * 4;
    *(float4*)orow = make_float4(acc[0], acc[1], acc[2], acc[3]);
  }
}

// ---------------- fallback: atomic scatter (small ws) ----------------
__global__ void scatter_kernel(const float* __restrict__ x, const float* __restrict__ W,
                               const int* __restrict__ src, const int* __restrict__ dst,
                               const float* __restrict__ w, long long total,
                               float* __restrict__ out) {
  long long i = (long long)blockIdx.x * blockDim.x + threadIdx.x;
  if (i < total) {
    int e = (int)(i >> 7);
    int c = (int)(i & 127);
    float acc = 0.f;
    const float* xr = &x[(size_t)src[e] * DIN];
    for (int k = 0; k < DIN; k++) acc += xr[k] * W[(size_t)k * DOUT + c];
    atomicAdd(&out[(size_t)dst[e] * DOUT + c], w[e] * acc);
  }
}

extern "C" void kernel_launch(void* const* d_in, const int* in_sizes, int n_in,
                              void* d_out, int out_size, void* d_ws, size_t ws_size,
                              hipStream_t stream) {
  const float* x = (const float*)d_in[0];
  const int* esrc = (const int*)d_in[1];
  const int* edst = (const int*)d_in[2];
  const float* ew = (const float*)d_in[3];
  const float* W = (const float*)d_in[4];
  float* out = (float*)d_out;

  const int N = in_sizes[0] / DIN;   // 100000
  const int E = in_sizes[1];         // 3200000
  const int nsb = (N + SB_NODES - 1) / SB_NODES;  // 98
  const int nsb8 = (nsb + 7) / 8;

  char* ws = (char*)d_ws;
  size_t off = 0;
  auto alloc = [&](size_t bytes) {
    size_t o = off;
    off = (off + bytes + 255) & ~(size_t)255;
    return o;
  };
  size_t sup_off = alloc((size_t)N * DOUT * 2);     // bf16 support table
  size_t wt_off = alloc((size_t)DOUT * DIN * 2);    // bf16 W^T
  size_t rp_off = alloc((size_t)(N + 1) * 4);
  size_t sbt_off = alloc(MAX_NSB * 4);
  size_t sbb_off = alloc(MAX_NSB * 4);
  size_t sbc_off = alloc(MAX_NSB * 4);
  size_t binq_off = alloc((size_t)E * 4);
  size_t binl_off = alloc((size_t)E * 2);
  size_t chist_off = alloc((size_t)nsb * CH * SB_NODES * 4);
  size_t csr_off = alloc((size_t)E * 4);
  bool use_csr = (off <= ws_size);

  unsigned short* support = (unsigned short*)(ws + sup_off);
  unsigned short* Wt = (unsigned short*)(ws + wt_off);
  int* row_ptr = (int*)(ws + rp_off);
  int* sb_tot = (int*)(ws + sbt_off);
  int* sb_base = (int*)(ws + sbb_off);
  int* sb_cur = (int*)(ws + sbc_off);
  unsigned* binq = (unsigned*)(ws + binq_off);
  unsigned short* binl = (unsigned short*)(ws + binl_off);
  int* chist = (int*)(ws + chist_off);
  unsigned* csr = (unsigned*)(ws + csr_off);

  if (use_csr) {
    wtrans_kernel<<<8, 256, 0, stream>>>(W, Wt);
    gemm_mfma_kernel<<<(N + 63) / 64, 256, 0, stream>>>(x, Wt, support, N);
    hipMemsetAsync(sb_tot, 0, MAX_NSB * 4, stream);
    sbhist_kernel<<<512, 256, 0, stream>>>(edst, E, nsb, sb_tot);
    sbscan_kernel<<<1, 128, 0, stream>>>(sb_tot, nsb, sb_base, sb_cur);
    bin1_kernel<<<(E + TILE - 1) / TILE, 256, 0, stream>>>(esrc, edst, ew, E, nsb,
                                                           sb_cur, binq, binl);
    histC_kernel<<<8 * nsb8 * CH, 256, 0, stream>>>(binl, sb_base, sb_tot, nsb, nsb8,
                                                    chist);
    rowscanC_kernel<<<nsb, 256, 0, stream>>>(chist, sb_base, N, E, nsb, row_ptr);
    scatterC_kernel<<<8 * nsb8 * CH, 256, 0, stream>>>(binq, binl, sb_base, sb_tot,
                                                       chist, nsb, nsb8, csr);
    spmm_kernel<<<(N + 3) / 4, 256, 0, stream>>>((const unsigned*)support, row_ptr, csr,
                                                 out, N, 0);
    spmm_kernel<<<(N + 3) / 4, 256, 0, stream>>>((const unsigned*)support, row_ptr, csr,
                                                 out, N, 1);
  } else {
    hipMemsetAsync(out, 0, (size_t)N * DOUT * 4, stream);
    long long total = (long long)E * DOUT;
    scatter_kernel<<<(int)((total + 255) / 256), 256, 0, stream>>>(x, W, esrc, edst, ew,
                                                                   total, out);
  }
}

// Round 6
// 409.983 us; speedup vs baseline: 1.0528x; 1.0528x over previous
//
#include <hip/hip_runtime.h>

// GraphConvolution: out = segment_sum_dst( w_e * (x @ W)[src_e] )
// N=100000 nodes, E=3200000 edges, D_IN=256, D_OUT=128, fp32 in/out.
// support stored bf16 row-major [N][128].
// GEMM (v5): bf16 MFMA 16x16x32, LDS-free, 32 rows/wave, FULL A-panel
//   register preload. LESSON (rounds 4-5): kernel is latency-bound on the
//   A-load->pack->MFMA chain; more waves made it WORSE (66->87us when
//   occupancy doubled). Fix = per-wave ILP: issue all 32 independent A
//   float4 loads up front (32KB in flight/wave), then MFMA loop waits only
//   on L2-resident B. v3=66us(2-step window), v4=87us(more waves).
// SpMM: TWO sequential column-half passes (12.8MB gather footprint each ->
//       higher per-XCD L2 hit rate); CSR recs 4B (src17|w15 fixed-point).
// CSR build (v3): chunked two-phase per-SB sort, LDS atomics ONLY.
//   LESSON (round 1): O(E) global atomics = device-scope RMW at the
//   coherence point (~64B HBM-side op each) -> 195MB traffic, 178us. Never.

#define DIN 256
#define DOUT 128
#define SB_SHIFT 10
#define SB_NODES 1024
#define MAX_NSB 128
#define TILE 4096
#define CH 8

__device__ __forceinline__ unsigned pack_bf16x2(float a, float b) {
  unsigned ua = __float_as_uint(a);
  unsigned ub = __float_as_uint(b);
  ua += 0x7fffu + ((ua >> 16) & 1u);   // round-to-nearest-even
  ub += 0x7fffu + ((ub >> 16) & 1u);
  return (ua >> 16) | (ub & 0xffff0000u);
}
__device__ __forceinline__ unsigned short bf16_rne(float a) {
  unsigned ua = __float_as_uint(a);
  ua += 0x7fffu + ((ua >> 16) & 1u);
  return (unsigned short)(ua >> 16);
}
__device__ __forceinline__ float bf_lo(unsigned p) { return __uint_as_float(p << 16); }
__device__ __forceinline__ float bf_hi(unsigned p) { return __uint_as_float(p & 0xffff0000u); }

typedef __attribute__((ext_vector_type(8))) short bf16x8;
typedef __attribute__((ext_vector_type(4))) float f32x4;

// ---------------- W transpose: W[256][128] fp32 -> Wt[128][256] bf16 -------
__global__ __launch_bounds__(256) void wtrans_kernel(const float* __restrict__ W,
                                                     unsigned short* __restrict__ Wt) {
  __shared__ float s[64][65];
  int t = threadIdx.x;
  int kt = blockIdx.x >> 1;
  int nt = blockIdx.x & 1;
#pragma unroll
  for (int i = 0; i < 16; i++) {
    int idx = i * 256 + t;
    int kk = idx >> 6, nn = idx & 63;
    s[kk][nn] = W[(size_t)(kt * 64 + kk) * DOUT + nt * 64 + nn];
  }
  __syncthreads();
#pragma unroll
  for (int i = 0; i < 16; i++) {
    int idx = i * 256 + t;
    int nn = idx >> 6, kk = idx & 63;
    Wt[(size_t)(nt * 64 + nn) * DIN + kt * 64 + kk] = bf16_rne(s[kk][nn]);
  }
}

// ---------------- GEMM: support = x @ W via bf16 MFMA, no LDS --------------
// v5: 32 rows/wave (2 row-tiles), 128 rows/block, 782 blocks.
// Phase 1: preload+pack ALL A (2 rt x 8 ksteps, 32 independent float4 loads).
// Phase 2: fully-unrolled MFMA loop; only B (L2-resident Wt) loads inside.
__global__ __launch_bounds__(256) void gemm_mfma_kernel(const float* __restrict__ x,
                                                        const unsigned short* __restrict__ Wt,
                                                        unsigned short* __restrict__ support,
                                                        int M) {
  const int lane = threadIdx.x & 63;
  const int wave = threadIdx.x >> 6;
  const int m = lane & 15, kg = lane >> 4;
  const int rowBase = blockIdx.x * 128 + wave * 32;

  f32x4 acc[2][8];
#pragma unroll
  for (int rt = 0; rt < 2; rt++)
#pragma unroll
    for (int ct = 0; ct < 8; ct++) acc[rt][ct] = (f32x4)(0.f);

  const float* arow[2];
#pragma unroll
  for (int rt = 0; rt < 2; rt++) {
    int r = rowBase + rt * 16 + m;
    if (r > M - 1) r = M - 1;
    arow[rt] = x + (size_t)r * DIN + kg * 8;
  }
  const unsigned short* brow[8];
#pragma unroll
  for (int ct = 0; ct < 8; ct++)
    brow[ct] = Wt + (size_t)(ct * 16 + m) * DIN + kg * 8;

  // ---- Phase 1: full A panel -> packed bf16 registers (64 VGPR) ----
  bf16x8 apack[2][8];
#pragma unroll
  for (int rt = 0; rt < 2; rt++) {
#pragma unroll
    for (int ks = 0; ks < 8; ks++) {
      float4 a0 = *(const float4*)(arow[rt] + ks * 32);
      float4 a1 = *(const float4*)(arow[rt] + ks * 32 + 4);
      union { bf16x8 f; unsigned u[4]; } ua;
      ua.u[0] = pack_bf16x2(a0.x, a0.y);
      ua.u[1] = pack_bf16x2(a0.z, a0.w);
      ua.u[2] = pack_bf16x2(a1.x, a1.y);
      ua.u[3] = pack_bf16x2(a1.z, a1.w);
      apack[rt][ks] = ua.f;
    }
  }

  // ---- Phase 2: MFMA loop, only B loads (Wt 64KB, L2-resident) ----
#pragma unroll
  for (int ks = 0; ks < 8; ks++) {
    bf16x8 bfr[8];
#pragma unroll
    for (int ct = 0; ct < 8; ct++) {
      union { bf16x8 f; uint4 u; } ub;
      ub.u = *(const uint4*)(brow[ct] + ks * 32);
      bfr[ct] = ub.f;
    }
#pragma unroll
    for (int rt = 0; rt < 2; rt++)
#pragma unroll
      for (int ct = 0; ct < 8; ct++)
        acc[rt][ct] = __builtin_amdgcn_mfma_f32_16x16x32_bf16(apack[rt][ks], bfr[ct],
                                                              acc[rt][ct], 0, 0, 0);
  }

#pragma unroll
  for (int rt = 0; rt < 2; rt++) {
#pragma unroll
    for (int r = 0; r < 4; r++) {
      int row = rowBase + rt * 16 + kg * 4 + r;
      if (row < M) {
#pragma unroll
        for (int ct = 0; ct < 8; ct++) {
          int col = ct * 16 + m;
          support[(size_t)row * DOUT + col] = bf16_rne(acc[rt][ct][r]);
        }
      }
    }
  }
}

// ---------------- super-bucket totals (LDS histogram, 98 counters) ---------
__global__ __launch_bounds__(256) void sbhist_kernel(const int* __restrict__ dst, int E,
                                                     int nsb, int* __restrict__ sb_tot) {
  __shared__ int h[MAX_NSB];
  int t = threadIdx.x;
  for (int i = t; i < nsb; i += 256) h[i] = 0;
  __syncthreads();
  int e4 = E >> 2;
  for (int i = blockIdx.x * 256 + t; i < e4; i += gridDim.x * 256) {
    int4 d = *(const int4*)&dst[i * 4];
    atomicAdd(&h[d.x >> SB_SHIFT], 1);
    atomicAdd(&h[d.y >> SB_SHIFT], 1);
    atomicAdd(&h[d.z >> SB_SHIFT], 1);
    atomicAdd(&h[d.w >> SB_SHIFT], 1);
  }
  if (blockIdx.x == 0 && t < (E & 3)) atomicAdd(&h[dst[e4 * 4 + t] >> SB_SHIFT], 1);
  __syncthreads();
  for (int i = t; i < nsb; i += 256)
    if (h[i]) atomicAdd(&sb_tot[i], h[i]);
}

// ---------------- exclusive scan of <=128 SB totals ------------------------
__global__ __launch_bounds__(128) void sbscan_kernel(const int* __restrict__ sb_tot, int nsb,
                                                     int* __restrict__ sb_base,
                                                     int* __restrict__ sb_cur) {
  __shared__ int s[128];
  int t = threadIdx.x;
  int v = (t < nsb) ? sb_tot[t] : 0;
  s[t] = v;
  __syncthreads();
  for (int off = 1; off < 128; off <<= 1) {
    int u = (t >= off) ? s[t - off] : 0;
    __syncthreads();
    s[t] += u;
    __syncthreads();
  }
  if (t < nsb) {
    int excl = s[t] - v;
    sb_base[t] = excl;
    sb_cur[t] = excl;
  }
}

// ---------------- bin1: LDS counting-sort by SB, coalesced chunk flush -----
// Emits split arrays: binq (final csr word src17|wq15) + binl (u16 local id).
__global__ __launch_bounds__(256) void bin1_kernel(const int* __restrict__ src,
                                                   const int* __restrict__ dst,
                                                   const float* __restrict__ w,
                                                   int E, int nsb,
                                                   int* __restrict__ sb_cur,
                                                   unsigned* __restrict__ binq,
                                                   unsigned short* __restrict__ binl) {
  __shared__ unsigned lq[TILE];
  __shared__ unsigned short ll[TILE];
  __shared__ unsigned short sbid[TILE];
  __shared__ int hist[MAX_NSB], segstart[MAX_NSB], cursor[MAX_NSB], sbbase[MAX_NSB];
  __shared__ int sc[128];
  int t = threadIdx.x;
  int e0 = blockIdx.x * TILE;
  int cnt = min(TILE, E - e0);

  for (int i = t; i < nsb; i += 256) hist[i] = 0;
  __syncthreads();
  for (int k = 0; k < TILE / 256; k++) {
    int e = e0 + k * 256 + t;
    if (e < E) atomicAdd(&hist[dst[e] >> SB_SHIFT], 1);
  }
  __syncthreads();
  if (t < 128) sc[t] = (t < nsb) ? hist[t] : 0;
  __syncthreads();
  for (int off = 1; off < 128; off <<= 1) {
    int v = 0;
    if (t < 128 && t >= off) v = sc[t - off];
    __syncthreads();
    if (t < 128) sc[t] += v;
    __syncthreads();
  }
  if (t < nsb) {
    int c = hist[t];
    int excl = sc[t] - c;
    segstart[t] = excl;
    cursor[t] = excl;
    if (c > 0) sbbase[t] = atomicAdd(&sb_cur[t], c);
  }
  __syncthreads();
  for (int k = 0; k < TILE / 256; k++) {
    int e = e0 + k * 256 + t;
    if (e < E) {
      int d = dst[e];
      int sb = d >> SB_SHIFT;
      int slot = atomicAdd(&cursor[sb], 1);
      float wf = w[e];
      unsigned wq = (unsigned)(wf * 32767.f + 0.5f);
      if (wq > 32767u) wq = 32767u;
      lq[slot] = (unsigned)src[e] | (wq << 17);
      ll[slot] = (unsigned short)(d & (SB_NODES - 1));
      sbid[slot] = (unsigned short)sb;
    }
  }
  __syncthreads();
  for (int k = 0; k < TILE / 256; k++) {
    int slot = k * 256 + t;
    if (slot < cnt) {
      int sb = sbid[slot];
      int p = sbbase[sb] + (slot - segstart[sb]);
      binq[p] = lq[slot];
      binl[p] = ll[slot];
    }
  }
}

// ---- XCD-grouped (sb,chunk) mapping: blockIdx ≡ sb (mod 8) so all 8 ------
// chunks of one SB land on the same XCD (csr window stays in one L2).
__device__ __forceinline__ bool sb_chunk(int g, int nsb, int nsb8, int& sb, int& c) {
  int xcd = g & 7;
  int i = g >> 3;
  sb = xcd + 8 * (i % nsb8);
  c = i / nsb8;
  return sb < nsb;
}

// ---------------- histC: per-(SB,chunk) node histogram (LDS) ---------------
__global__ __launch_bounds__(256) void histC_kernel(const unsigned short* __restrict__ binl,
                                                    const int* __restrict__ sb_base,
                                                    const int* __restrict__ sb_tot,
                                                    int nsb, int nsb8,
                                                    int* __restrict__ chist) {
  __shared__ int h[SB_NODES];
  int sb, c;
  if (!sb_chunk(blockIdx.x, nsb, nsb8, sb, c)) return;
  int t = threadIdx.x;
  for (int l = t; l < SB_NODES; l += 256) h[l] = 0;
  __syncthreads();
  int beg = sb_base[sb], len = sb_tot[sb];
  int per = (len + CH - 1) / CH;
  int lo = beg + min(len, c * per);
  int hi = beg + min(len, (c + 1) * per);
  for (int e = lo + t; e < hi; e += 256)
    atomicAdd(&h[binl[e]], 1);
  __syncthreads();
  int* dstp = chist + ((size_t)sb * CH + c) * SB_NODES;
  for (int l = t; l < SB_NODES; l += 256) dstp[l] = h[l];
}

// ---------------- rowscanC: per-SB scan -> row_ptr + absolute cursors ------
__global__ __launch_bounds__(256) void rowscanC_kernel(int* __restrict__ chist,
                                                       const int* __restrict__ sb_base,
                                                       int N, int E, int nsb,
                                                       int* __restrict__ row_ptr) {
  __shared__ int part[256];
  int sb = blockIdx.x;
  int t = threadIdx.x;
  int* base = chist + (size_t)sb * CH * SB_NODES;
  int cnt[4][CH];
  int tsum = 0;
#pragma unroll
  for (int u = 0; u < 4; u++) {
    int l = 4 * t + u;
#pragma unroll
    for (int c = 0; c < CH; c++) {
      int v = base[c * SB_NODES + l];
      cnt[u][c] = v;
      tsum += v;
    }
  }
  part[t] = tsum;
  __syncthreads();
  for (int off = 1; off < 256; off <<= 1) {
    int v = (t >= off) ? part[t - off] : 0;
    __syncthreads();
    part[t] += v;
    __syncthreads();
  }
  int run = sb_base[sb] + part[t] - tsum;
  int nodeBase = sb << SB_SHIFT;
#pragma unroll
  for (int u = 0; u < 4; u++) {
    int l = 4 * t + u;
    int node = nodeBase + l;
    if (node < N) row_ptr[node] = run;
#pragma unroll
    for (int c = 0; c < CH; c++) {
      base[c * SB_NODES + l] = run;
      run += cnt[u][c];
    }
  }
  if (sb == nsb - 1 && t == 0) row_ptr[N] = E;
}

// ---------------- scatterC: single read, LDS cursors, direct csr copy ------
__global__ __launch_bounds__(256) void scatterC_kernel(const unsigned* __restrict__ binq,
                                                       const unsigned short* __restrict__ binl,
                                                       const int* __restrict__ sb_base,
                                                       const int* __restrict__ sb_tot,
                                                       const int* __restrict__ chist,
                                                       int nsb, int nsb8,
                                                       unsigned* __restrict__ csr) {
  __shared__ int cur[SB_NODES];
  int sb, c;
  if (!sb_chunk(blockIdx.x, nsb, nsb8, sb, c)) return;
  int t = threadIdx.x;
  const int* cb = chist + ((size_t)sb * CH + c) * SB_NODES;
  for (int l = t; l < SB_NODES; l += 256) cur[l] = cb[l];
  __syncthreads();
  int beg = sb_base[sb], len = sb_tot[sb];
  int per = (len + CH - 1) / CH;
  int lo = beg + min(len, c * per);
  int hi = beg + min(len, (c + 1) * per);
  for (int e = lo + t; e < hi; e += 256) {
    int l = binl[e];
    int pos = atomicAdd(&cur[l], 1);
    csr[pos] = binq[e];
  }
}

// ---------------- gather SpMM v3: column-half pass, wave per node ----------
// pass p gathers only 128B (cols p*64..p*64+63) per edge -> 12.8MB footprint.
// wave = 4 edge-groups x 16 col-lanes; lane loads uint2 (4 cols).
__global__ __launch_bounds__(256) void spmm_kernel(const unsigned* __restrict__ sup,
                                                   const int* __restrict__ row_ptr,
                                                   const unsigned* __restrict__ csr,
                                                   float* __restrict__ out, int N,
                                                   int pass) {
  int wave = threadIdx.x >> 6;
  int lane = threadIdx.x & 63;
  int g = lane >> 4;        // edge subgroup 0..3
  int c = lane & 15;        // col chunk: uint2 -> cols pass*64 + c*4 ..+3
  int node = blockIdx.x * 4 + wave;
  if (node >= N) return;
  int j0 = row_ptr[node];
  int j1 = row_ptr[node + 1];
  const unsigned* supb = sup + pass * 32 + c * 2;
  float acc[4] = {0.f, 0.f, 0.f, 0.f};
  const float wscale = 1.f / 32767.f;

  for (int base = j0; base < j1; base += 64) {
    int cnt = min(64, j1 - base);
    unsigned myrec = 0;
    if (lane < cnt) myrec = csr[base + lane];
    for (int j = 0; j < cnt; j += 16) {
      uint2 p[4];
      float wv[4];
#pragma unroll
      for (int u = 0; u < 4; u++) {
        int e = j + 4 * u + g;
        int jj = min(e, cnt - 1);
        unsigned r = (unsigned)__shfl((int)myrec, jj, 64);
        int s = (int)(r & 0x1FFFFu);
        float ww = (float)(r >> 17) * wscale;
        wv[u] = (e < cnt) ? ww : 0.f;
        p[u] = *(const uint2*)(supb + (size_t)s * 64);
      }
#pragma unroll
      for (int u = 0; u < 4; u++) {
        acc[0] += wv[u] * bf_lo(p[u].x);
        acc[1] += wv[u] * bf_hi(p[u].x);
        acc[2] += wv[u] * bf_lo(p[u].y);
        acc[3] += wv[u] * bf_hi(p[u].y);
      }
    }
  }
#pragma unroll
  for (int i = 0; i < 4; i++) {
    acc[i] += __shfl_xor(acc[i], 16, 64);
    acc[i] += __shfl_xor(acc[i], 32, 64);
  }
  if (g == 0) {
    float* orow = out + (size_t)node * DOUT + pass * 64 + c * 4;
    *(float4*)orow = make_float4(acc[0], acc[1], acc[2], acc[3]);
  }
}

// ---------------- fallback: atomic scatter (small ws) ----------------
__global__ void scatter_kernel(const float* __restrict__ x, const float* __restrict__ W,
                               const int* __restrict__ src, const int* __restrict__ dst,
                               const float* __restrict__ w, long long total,
                               float* __restrict__ out) {
  long long i = (long long)blockIdx.x * blockDim.x + threadIdx.x;
  if (i < total) {
    int e = (int)(i >> 7);
    int c = (int)(i & 127);
    float acc = 0.f;
    const float* xr = &x[(size_t)src[e] * DIN];
    for (int k = 0; k < DIN; k++) acc += xr[k] * W[(size_t)k * DOUT + c];
    atomicAdd(&out[(size_t)dst[e] * DOUT + c], w[e] * acc);
  }
}

extern "C" void kernel_launch(void* const* d_in, const int* in_sizes, int n_in,
                              void* d_out, int out_size, void* d_ws, size_t ws_size,
                              hipStream_t stream) {
  const float* x = (const float*)d_in[0];
  const int* esrc = (const int*)d_in[1];
  const int* edst = (const int*)d_in[2];
  const float* ew = (const float*)d_in[3];
  const float* W = (const float*)d_in[4];
  float* out = (float*)d_out;

  const int N = in_sizes[0] / DIN;   // 100000
  const int E = in_sizes[1];         // 3200000
  const int nsb = (N + SB_NODES - 1) / SB_NODES;  // 98
  const int nsb8 = (nsb + 7) / 8;

  char* ws = (char*)d_ws;
  size_t off = 0;
  auto alloc = [&](size_t bytes) {
    size_t o = off;
    off = (off + bytes + 255) & ~(size_t)255;
    return o;
  };
  size_t sup_off = alloc((size_t)N * DOUT * 2);     // bf16 support table
  size_t wt_off = alloc((size_t)DOUT * DIN * 2);    // bf16 W^T
  size_t rp_off = alloc((size_t)(N + 1) * 4);
  size_t sbt_off = alloc(MAX_NSB * 4);
  size_t sbb_off = alloc(MAX_NSB * 4);
  size_t sbc_off = alloc(MAX_NSB * 4);
  size_t binq_off = alloc((size_t)E * 4);
  size_t binl_off = alloc((size_t)E * 2);
  size_t chist_off = alloc((size_t)nsb * CH * SB_NODES * 4);
  size_t csr_off = alloc((size_t)E * 4);
  bool use_csr = (off <= ws_size);

  unsigned short* support = (unsigned short*)(ws + sup_off);
  unsigned short* Wt = (unsigned short*)(ws + wt_off);
  int* row_ptr = (int*)(ws + rp_off);
  int* sb_tot = (int*)(ws + sbt_off);
  int* sb_base = (int*)(ws + sbb_off);
  int* sb_cur = (int*)(ws + sbc_off);
  unsigned* binq = (unsigned*)(ws + binq_off);
  unsigned short* binl = (unsigned short*)(ws + binl_off);
  int* chist = (int*)(ws + chist_off);
  unsigned* csr = (unsigned*)(ws + csr_off);

  if (use_csr) {
    wtrans_kernel<<<8, 256, 0, stream>>>(W, Wt);
    gemm_mfma_kernel<<<(N + 127) / 128, 256, 0, stream>>>(x, Wt, support, N);
    hipMemsetAsync(sb_tot, 0, MAX_NSB * 4, stream);
    sbhist_kernel<<<512, 256, 0, stream>>>(edst, E, nsb, sb_tot);
    sbscan_kernel<<<1, 128, 0, stream>>>(sb_tot, nsb, sb_base, sb_cur);
    bin1_kernel<<<(E + TILE - 1) / TILE, 256, 0, stream>>>(esrc, edst, ew, E, nsb,
                                                           sb_cur, binq, binl);
    histC_kernel<<<8 * nsb8 * CH, 256, 0, stream>>>(binl, sb_base, sb_tot, nsb, nsb8,
                                                    chist);
    rowscanC_kernel<<<nsb, 256, 0, stream>>>(chist, sb_base, N, E, nsb, row_ptr);
    scatterC_kernel<<<8 * nsb8 * CH, 256, 0, stream>>>(binq, binl, sb_base, sb_tot,
                                                       chist, nsb, nsb8, csr);
    spmm_kernel<<<(N + 3) / 4, 256, 0, stream>>>((const unsigned*)support, row_ptr, csr,
                                                 out, N, 0);
    spmm_kernel<<<(N + 3) / 4, 256, 0, stream>>>((const unsigned*)support, row_ptr, csr,
                                                 out, N, 1);
  } else {
    hipMemsetAsync(out, 0, (size_t)N * DOUT * 4, stream);
    long long total = (long long)E * DOUT;
    scatter_kernel<<<(int)((total + 255) / 256), 256, 0, stream>>>(x, W, esrc, edst, ew,
                                                                   total, out);
  }
}